// Round 7
// baseline (592.840 us; speedup 1.0000x reference)
//
#include <hip/hip_runtime.h>
#include <hip/hip_bf16.h>
#include <math.h>

// Problem constants (B=64, N=512, D=512, H=4D=2048, R=32 routes)
#define B_ 64
#define N_ 512
#define D_ 512
#define H_ 2048
#define R_ 32
#define M_ (B_ * N_)  // 32768 token rows

typedef __bf16 bf16x8 __attribute__((ext_vector_type(8)));
typedef float f32x4 __attribute__((ext_vector_type(4)));

__device__ __forceinline__ void async_ld16(const void* g, void* l) {
  __builtin_amdgcn_global_load_lds((__attribute__((address_space(1))) void*)g,
                                   (__attribute__((address_space(3))) void*)l,
                                   16, 0, 0);
}

// gelu via A&S 7.1.28 erf: 1 - 1/p^16, p = 1 + sum a_k x^k. |err| <= 3e-7.
// Polynomial + 4 squarings + 1 rcp — NO exp (was 2 transcendentals).
__device__ __forceinline__ float fast_gelu(float v) {
  const float s = v * 0.70710678118654752f;
  const float a = fabsf(s);
  float t = fmaf(a, 4.30638e-5f, 2.765672e-4f);
  t = fmaf(a, t, 1.520143e-4f);
  t = fmaf(a, t, 9.2705272e-3f);
  t = fmaf(a, t, 4.22820123e-2f);
  t = fmaf(a, t, 7.05230784e-2f);
  const float p = fmaf(a, t, 1.0f);
  float p16 = p * p;     // p^2
  p16 = p16 * p16;       // p^4
  p16 = p16 * p16;       // p^8
  p16 = p16 * p16;       // p^16
  const float er = 1.0f - __builtin_amdgcn_rcpf(p16);
  const float erfs = (s >= 0.f) ? er : -er;
  return 0.5f * v * (1.0f + erfs);
}

// ---------------------------------------------------------------------------
// PREP (one launch): bid 0 = mask dtype detect + zero done-counter;
// bid 1..512 = w1/w2 transpose+cast; bid 513..4608 = LayerNorm rows -> bf16.
// ---------------------------------------------------------------------------
__global__ __launch_bounds__(512) void prep_kernel(
    const float* __restrict__ tokens, const void* __restrict__ mask_raw,
    const float* __restrict__ ln1_g, const float* __restrict__ ln1_b,
    const float* __restrict__ w1, const float* __restrict__ w2,
    __hip_bfloat16* __restrict__ aBf, __hip_bfloat16* __restrict__ w1t,
    __hip_bfloat16* __restrict__ w2t, int* __restrict__ flag) {
  const int bid = blockIdx.x;
  const int tid = threadIdx.x;
  if (bid == 0) {
    __shared__ int f;
    if (tid == 0) f = 0;
    __syncthreads();
    const uint4* p = (const uint4*)mask_raw;
    unsigned acc = 0;
    for (int k = tid; k < M_ / 16; k += 512) {
      const uint4 v = p[k];
      acc |= (v.x | v.y | v.z | v.w) & 0xFFFFFF00u;
    }
    if (acc) f = 1;  // benign race
    __syncthreads();
    if (tid == 0) {
      flag[0] = f;
      flag[1] = 0;  // route_pool completion counter
    }
  } else if (bid <= 512) {
    __shared__ float tile[64][65];
    const int t = bid - 1;
    const float* src;
    __hip_bfloat16* dst;
    int R, C, cx, ry;
    if (t < 256) { src = w1; dst = w1t; R = 512; C = 2048; cx = t & 31; ry = t >> 5; }
    else { const int t2 = t - 256; src = w2; dst = w2t; R = 2048; C = 512; cx = t2 & 7; ry = t2 >> 3; }
    const int c0 = cx * 64, r0 = ry * 64;
    const int tx = tid & 63, ty = tid >> 6;
    for (int r = ty; r < 64; r += 8)
      tile[r][tx] = src[(size_t)(r0 + r) * C + c0 + tx];
    __syncthreads();
    for (int r = ty; r < 64; r += 8)
      dst[(size_t)(c0 + r) * R + r0 + tx] = __float2bfloat16(tile[tx][r]);
  } else {
    const int wv = tid >> 6, lane = tid & 63;
    const int row = (bid - 513) * 8 + wv;
    const float* p = tokens + (size_t)row * D_ + lane * 8;
    const float4 v0 = *(const float4*)p;
    const float4 v1 = *(const float4*)(p + 4);
    float s = v0.x + v0.y + v0.z + v0.w + v1.x + v1.y + v1.z + v1.w;
    float ss = v0.x * v0.x + v0.y * v0.y + v0.z * v0.z + v0.w * v0.w +
               v1.x * v1.x + v1.y * v1.y + v1.z * v1.z + v1.w * v1.w;
#pragma unroll
    for (int m = 32; m > 0; m >>= 1) {
      s += __shfl_xor(s, m);
      ss += __shfl_xor(ss, m);
    }
    const float mu = s * (1.0f / D_);
    const float rstd = rsqrtf(ss * (1.0f / D_) - mu * mu + 1e-5f);
    const float4 g0 = *(const float4*)(ln1_g + lane * 8);
    const float4 g1 = *(const float4*)(ln1_g + lane * 8 + 4);
    const float4 b0 = *(const float4*)(ln1_b + lane * 8);
    const float4 b1 = *(const float4*)(ln1_b + lane * 8 + 4);
    const float vv[8] = {v0.x, v0.y, v0.z, v0.w, v1.x, v1.y, v1.z, v1.w};
    const float gg[8] = {g0.x, g0.y, g0.z, g0.w, g1.x, g1.y, g1.z, g1.w};
    const float bb[8] = {b0.x, b0.y, b0.z, b0.w, b1.x, b1.y, b1.z, b1.w};
    union { __hip_bfloat16 h[8]; uint4 u; } pk;
#pragma unroll
    for (int t2 = 0; t2 < 8; ++t2)
      pk.h[t2] = __float2bfloat16((vv[t2] - mu) * rstd * gg[t2] + bb[t2]);
    *(uint4*)(aBf + (size_t)row * D_ + lane * 8) = pk.u;
  }
}

// ---------------------------------------------------------------------------
// GEMM1: C = gelu(A @ Bt^T + bias). 128x128 tile, BK=64 (32 MFMA/barrier).
// Conflict-free staging (global-side k-chunk XOR) + single-pass LDS-restage
// epilogue with packed bf16 cvt (v_cvt_pk_bf16_f32 via __float22bfloat162_rn).
// ---------------------------------------------------------------------------
__global__ __launch_bounds__(256, 2) void gemm_bias_gelu_kernel(
    const __hip_bfloat16* __restrict__ A, const __hip_bfloat16* __restrict__ Bt,
    const float* __restrict__ bias, __hip_bfloat16* __restrict__ C,
    int K, int ldc, int NC) {
  __shared__ alignas(16) unsigned short SU[16384];  // 32 KB: As | Bs (128x64 each)
  unsigned short* As = SU;
  unsigned short* Bs = SU + 8192;
  const int tid = threadIdx.x;
  const int w = tid >> 6;
  const int lane = tid & 63;
  const int bid = blockIdx.x;
  const int rowT = (bid / (NC * 8)) * 8 + (bid & 7);
  const int colT = (bid >> 3) % NC;
  const int rowBase = rowT * 128;
  const int colBase = colT * 128;
  const int warpRow = w >> 1;
  const int warpCol = w & 1;
  const int q = lane >> 4;
  const int mr = lane & 15;
  const int srow8 = lane >> 3;
  const int sg8 = ((lane & 7) ^ srow8) * 8;
  const int mx7 = (mr & 7) * 8;

  f32x4 acc[4][4] = {};

  for (int k0 = 0; k0 < K; k0 += 64) {
    __syncthreads();
    {
      const __hip_bfloat16* Ak = A + (size_t)(rowBase + w * 32 + srow8) * K + k0 + sg8;
      const __hip_bfloat16* Bk = Bt + (size_t)(colBase + w * 32 + srow8) * K + k0 + sg8;
#pragma unroll
      for (int i = 0; i < 4; ++i) {
        async_ld16(Ak + (size_t)(i * 8) * K, (void*)&As[(w * 32 + i * 8) * 64]);
        async_ld16(Bk + (size_t)(i * 8) * K, (void*)&Bs[(w * 32 + i * 8) * 64]);
      }
    }
    __syncthreads();
#pragma unroll
    for (int s = 0; s < 2; ++s) {
      bf16x8 af[4], bf[4];
#pragma unroll
      for (int i = 0; i < 4; ++i)
        af[i] = *reinterpret_cast<const bf16x8*>(
            &As[(warpRow * 64 + i * 16 + mr) * 64 + (((s * 4 + q) * 8) ^ mx7)]);
#pragma unroll
      for (int j = 0; j < 4; ++j)
        bf[j] = *reinterpret_cast<const bf16x8*>(
            &Bs[(warpCol * 64 + j * 16 + mr) * 64 + (((s * 4 + q) * 8) ^ mx7)]);
#pragma unroll
      for (int i = 0; i < 4; ++i)
#pragma unroll
        for (int j = 0; j < 4; ++j)
          acc[i][j] = __builtin_amdgcn_mfma_f32_16x16x32_bf16(af[i], bf[j], acc[i][j], 0, 0, 0);
    }
  }

  // ---- single-pass epilogue: full 128x128 bf16 tile in 32 KB LDS ----
  __syncthreads();
  __hip_bfloat16* SB = (__hip_bfloat16*)SU;
#pragma unroll
  for (int j = 0; j < 4; ++j) {
    const int col = warpCol * 64 + j * 16 + mr;
    const float bv = bias[colBase + col];
    const int cl = col & 7;
    const int ch = col >> 3;
#pragma unroll
    for (int i = 0; i < 4; ++i) {
      float g[4];
#pragma unroll
      for (int r = 0; r < 4; ++r) g[r] = fast_gelu(acc[i][j][r] + bv);
      const __hip_bfloat162 p01 = __float22bfloat162_rn(make_float2(g[0], g[1]));
      const __hip_bfloat162 p23 = __float22bfloat162_rn(make_float2(g[2], g[3]));
      const int row0 = warpRow * 64 + i * 16 + q * 4;
      SB[(row0 + 0) * 128 + ((ch ^ ((row0 + 0) & 7)) << 3) + cl] = p01.x;
      SB[(row0 + 1) * 128 + ((ch ^ ((row0 + 1) & 7)) << 3) + cl] = p01.y;
      SB[(row0 + 2) * 128 + ((ch ^ ((row0 + 2) & 7)) << 3) + cl] = p23.x;
      SB[(row0 + 3) * 128 + ((ch ^ ((row0 + 3) & 7)) << 3) + cl] = p23.y;
    }
  }
  __syncthreads();
  const int lg = tid & 15, rsub = tid >> 4;
#pragma unroll
  for (int it = 0; it < 8; ++it) {
    const int m = it * 16 + rsub;
    const int slot = lg ^ (m & 7);
    const uint4 val = *(const uint4*)&SB[m * 128 + slot * 8];
    *(uint4*)&C[(size_t)(rowBase + m) * ldc + colBase + lg * 8] = val;
  }
}

// ---------------------------------------------------------------------------
// GEMM2: X = resid + bias + A @ Bt^T  (fp32 out w/ residual). BK=64,
// 256x128 tile, 512 threads (8 waves).
// ---------------------------------------------------------------------------
__global__ __launch_bounds__(512, 4) void gemm_acc_kernel(
    const __hip_bfloat16* __restrict__ A, const __hip_bfloat16* __restrict__ Bt,
    const float* __restrict__ bias, const float* __restrict__ resid,
    float* __restrict__ X, int K, int ldb, int first) {
  __shared__ alignas(16) unsigned short SU[24576];  // 48 KB: As 256x64 | Bs 128x64
  unsigned short* As = SU;
  unsigned short* Bs = SU + 16384;
  const int tid = threadIdx.x;
  const int w = tid >> 6;
  const int lane = tid & 63;
  const int bid = blockIdx.x;
  const int NC = 4;
  const int rowT = (bid / (NC * 8)) * 8 + (bid & 7);
  const int colT = (bid >> 3) % NC;
  const int rowBase = rowT * 256;
  const int colBase = colT * 128;
  const int warpRow = w >> 1;
  const int warpCol = w & 1;
  const int q = lane >> 4;
  const int mr = lane & 15;
  const int srow8 = lane >> 3;
  const int sg8 = ((lane & 7) ^ srow8) * 8;
  const int mx7 = (mr & 7) * 8;

  f32x4 acc[4][4] = {};

  for (int k0 = 0; k0 < K; k0 += 64) {
    __syncthreads();
    {
      const __hip_bfloat16* Ak = A + (size_t)(rowBase + w * 32 + srow8) * K + k0 + sg8;
#pragma unroll
      for (int i = 0; i < 4; ++i)
        async_ld16(Ak + (size_t)(i * 8) * K, (void*)&As[(w * 32 + i * 8) * 64]);
      const __hip_bfloat16* Bk = Bt + (size_t)(colBase + w * 16 + srow8) * ldb + k0 + sg8;
#pragma unroll
      for (int i = 0; i < 2; ++i)
        async_ld16(Bk + (size_t)(i * 8) * ldb, (void*)&Bs[(w * 16 + i * 8) * 64]);
    }
    __syncthreads();
#pragma unroll
    for (int s = 0; s < 2; ++s) {
      bf16x8 af[4], bf[4];
#pragma unroll
      for (int i = 0; i < 4; ++i)
        af[i] = *reinterpret_cast<const bf16x8*>(
            &As[(warpRow * 64 + i * 16 + mr) * 64 + (((s * 4 + q) * 8) ^ mx7)]);
#pragma unroll
      for (int j = 0; j < 4; ++j)
        bf[j] = *reinterpret_cast<const bf16x8*>(
            &Bs[(warpCol * 64 + j * 16 + mr) * 64 + (((s * 4 + q) * 8) ^ mx7)]);
#pragma unroll
      for (int i = 0; i < 4; ++i)
#pragma unroll
        for (int j = 0; j < 4; ++j)
          acc[i][j] = __builtin_amdgcn_mfma_f32_16x16x32_bf16(af[i], bf[j], acc[i][j], 0, 0, 0);
    }
  }

#pragma unroll
  for (int j = 0; j < 4; ++j) {
    const int n = colBase + warpCol * 64 + j * 16 + mr;
    const float bv = bias[n];
#pragma unroll
    for (int i = 0; i < 4; ++i) {
#pragma unroll
      for (int r = 0; r < 4; ++r) {
        const int m = rowBase + warpRow * 64 + i * 16 + q * 4 + r;
        const size_t idx = (size_t)m * N_ + n;
        const float base = first ? (resid[idx] + bv) : X[idx];
        X[idx] = base + acc[i][j][r];
      }
    }
  }
}

// ---------------------------------------------------------------------------
// Fused per-(b,route) pool + (last 64 blocks) final route-level pool.
// Completion counter in flag[1] (zeroed by prep). Each block: release fence +
// atomicAdd; blocks receiving ordinal >= 1984 spin until all 2048 done, then
// run the final pool for one batch each. <=64 spinners vs 2048-block grid ->
// deadlock-free; device-scope atomics per G16.
// ---------------------------------------------------------------------------
__global__ __launch_bounds__(256) void route_pool_kernel(
    const float* __restrict__ X, const int* __restrict__ route_ids,
    const void* __restrict__ mask_raw, int* __restrict__ flag,
    const float* __restrict__ gw, const float* __restrict__ gb,
    const float* __restrict__ ww, const float* __restrict__ wbias,
    const float* __restrict__ rp_g, const float* __restrict__ rp_b,
    const float* __restrict__ rp_w, const float* __restrict__ rp_bias,
    float* __restrict__ routes, int* __restrict__ present,
    float* __restrict__ out) {
  const int b = blockIdx.x >> 5;
  const int r = blockIdx.x & 31;
  const int tid = threadIdx.x;
  __shared__ int cnt;
  __shared__ int sh_old;
  __shared__ int ls[N_];
  __shared__ float lw[N_];
  __shared__ float fsrl[R_];
  __shared__ float fsrw[R_];
  if (tid == 0) cnt = 0;
  __syncthreads();
  const int fl = flag[0];
  for (int n = tid; n < N_; n += 256) {
    const int mk = fl ? (int)((const unsigned char*)mask_raw)[b * N_ + n]
                      : ((const int*)mask_raw)[b * N_ + n];
    if (route_ids[n] == r && mk != 0) {
      int p = atomicAdd(&cnt, 1);
      ls[p] = n;
    }
  }
  __syncthreads();
  const int c = cnt;
  const int wv = tid >> 6, lane = tid & 63;
  for (int t = wv; t < c; t += 4) {
    const float* p = X + ((size_t)b * N_ + ls[t]) * D_ + lane * 8;
    const float4 v0 = *(const float4*)p;
    const float4 v1 = *(const float4*)(p + 4);
    float s = v0.x + v0.y + v0.z + v0.w + v1.x + v1.y + v1.z + v1.w;
    float ss = v0.x * v0.x + v0.y * v0.y + v0.z * v0.z + v0.w * v0.w +
               v1.x * v1.x + v1.y * v1.y + v1.z * v1.z + v1.w * v1.w;
#pragma unroll
    for (int m = 32; m > 0; m >>= 1) {
      s += __shfl_xor(s, m);
      ss += __shfl_xor(ss, m);
    }
    const float mu = s * (1.0f / D_);
    const float rstd = rsqrtf(ss * (1.0f / D_) - mu * mu + 1e-5f);
    const float4 g0 = *(const float4*)(gw + lane * 8);
    const float4 g1 = *(const float4*)(gw + lane * 8 + 4);
    const float4 b0 = *(const float4*)(gb + lane * 8);
    const float4 b1v = *(const float4*)(gb + lane * 8 + 4);
    const float4 w0 = *(const float4*)(ww + lane * 8);
    const float4 w1v = *(const float4*)(ww + lane * 8 + 4);
    const float vv[8] = {v0.x, v0.y, v0.z, v0.w, v1.x, v1.y, v1.z, v1.w};
    const float gg[8] = {g0.x, g0.y, g0.z, g0.w, g1.x, g1.y, g1.z, g1.w};
    const float bb[8] = {b0.x, b0.y, b0.z, b0.w, b1v.x, b1v.y, b1v.z, b1v.w};
    const float wwv[8] = {w0.x, w0.y, w0.z, w0.w, w1v.x, w1v.y, w1v.z, w1v.w};
    float a = 0.f;
#pragma unroll
    for (int t2 = 0; t2 < 8; ++t2) a += ((vv[t2] - mu) * rstd * gg[t2] + bb[t2]) * wwv[t2];
#pragma unroll
    for (int m = 32; m > 0; m >>= 1) a += __shfl_xor(a, m);
    if (lane == 0) lw[t] = a + wbias[0];
  }
  __syncthreads();
  if (tid == 0 && c > 0) {
    float mx = -1e30f;
    for (int i = 0; i < c; ++i) mx = fmaxf(mx, lw[i]);
    float sm = 0.f;
    for (int i = 0; i < c; ++i) {
      const float e = __expf(lw[i] - mx);
      lw[i] = e;
      sm += e;
    }
    const float inv = 1.0f / sm;
    for (int i = 0; i < c; ++i) lw[i] *= inv;
  }
  __syncthreads();
  float a0 = 0.f, a1 = 0.f;
  for (int i = 0; i < c; ++i) {
    const float* xr = X + ((size_t)b * N_ + ls[i]) * D_;
    const float wgt = lw[i];
    a0 += wgt * xr[tid];
    a1 += wgt * xr[tid + 256];
  }
  float* outp = routes + ((size_t)b * R_ + r) * D_;
  outp[tid] = a0;
  outp[tid + 256] = a1;
  if (tid == 0) present[b * R_ + r] = (c > 0) ? 1 : 0;

  // ---- completion protocol ----
  __threadfence();  // release this block's routes/present
  __syncthreads();
  if (tid == 0) sh_old = atomicAdd(&flag[1], 1);
  __syncthreads();
  const int old = sh_old;
  if (old < B_ * R_ - B_) return;
  const int bb = old - (B_ * R_ - B_);  // 0..63, each exactly once
  if (tid == 0) {
    while (atomicAdd(&flag[1], 0) < B_ * R_) __builtin_amdgcn_s_sleep(8);
  }
  __syncthreads();
  __threadfence();  // acquire all blocks' routes/present

  // ---- final pool for batch bb (256 threads, 4 waves) ----
  for (int rr = wv; rr < R_; rr += 4) {
    const float* p = routes + ((size_t)bb * R_ + rr) * D_ + lane * 8;
    const float4 v0 = *(const float4*)p;
    const float4 v1 = *(const float4*)(p + 4);
    float s = v0.x + v0.y + v0.z + v0.w + v1.x + v1.y + v1.z + v1.w;
    float ss = v0.x * v0.x + v0.y * v0.y + v0.z * v0.z + v0.w * v0.w +
               v1.x * v1.x + v1.y * v1.y + v1.z * v1.z + v1.w * v1.w;
#pragma unroll
    for (int m = 32; m > 0; m >>= 1) {
      s += __shfl_xor(s, m);
      ss += __shfl_xor(ss, m);
    }
    const float mu = s * (1.0f / D_);
    const float rstd = rsqrtf(ss * (1.0f / D_) - mu * mu + 1e-5f);
    const float4 g0 = *(const float4*)(rp_g + lane * 8);
    const float4 g1 = *(const float4*)(rp_g + lane * 8 + 4);
    const float4 b0 = *(const float4*)(rp_b + lane * 8);
    const float4 b1v = *(const float4*)(rp_b + lane * 8 + 4);
    const float4 w0 = *(const float4*)(rp_w + lane * 8);
    const float4 w1v = *(const float4*)(rp_w + lane * 8 + 4);
    const float vv[8] = {v0.x, v0.y, v0.z, v0.w, v1.x, v1.y, v1.z, v1.w};
    const float gg[8] = {g0.x, g0.y, g0.z, g0.w, g1.x, g1.y, g1.z, g1.w};
    const float bb2[8] = {b0.x, b0.y, b0.z, b0.w, b1v.x, b1v.y, b1v.z, b1v.w};
    const float wwv[8] = {w0.x, w0.y, w0.z, w0.w, w1v.x, w1v.y, w1v.z, w1v.w};
    float a = 0.f;
#pragma unroll
    for (int t2 = 0; t2 < 8; ++t2) a += ((vv[t2] - mu) * rstd * gg[t2] + bb2[t2]) * wwv[t2];
#pragma unroll
    for (int m = 32; m > 0; m >>= 1) a += __shfl_xor(a, m);
    if (lane == 0) fsrl[rr] = a + rp_bias[0];
  }
  __syncthreads();
  if (tid == 0) {
    float mx = -1e30f;
    for (int rr = 0; rr < R_; ++rr)
      if (present[bb * R_ + rr]) mx = fmaxf(mx, fsrl[rr]);
    float sm = 0.f;
    for (int rr = 0; rr < R_; ++rr) {
      const float e = present[bb * R_ + rr] ? __expf(fsrl[rr] - mx) : 0.f;
      fsrw[rr] = e;
      sm += e;
    }
    const float inv = (sm > 0.f) ? 1.0f / sm : 0.f;
    for (int rr = 0; rr < R_; ++rr) fsrw[rr] *= inv;
  }
  __syncthreads();
  float o0 = 0.f, o1 = 0.f;
  for (int rr = 0; rr < R_; ++rr) {
    const float* rp = routes + ((size_t)bb * R_ + rr) * D_;
    o0 += fsrw[rr] * rp[tid];
    o1 += fsrw[rr] * rp[tid + 256];
  }
  out[(size_t)bb * D_ + tid] = o0;
  out[(size_t)bb * D_ + tid + 256] = o1;
}

// ---------------------------------------------------------------------------
extern "C" void kernel_launch(void* const* d_in, const int* in_sizes, int n_in,
                              void* d_out, int out_size, void* d_ws, size_t ws_size,
                              hipStream_t stream) {
  const float* tokens = (const float*)d_in[0];
  const void* mask_raw = d_in[1];
  const int* route_ids = (const int*)d_in[2];
  const float* ln1_g = (const float*)d_in[3];
  const float* ln1_b = (const float*)d_in[4];
  const float* w1 = (const float*)d_in[5];
  const float* b1 = (const float*)d_in[6];
  const float* w2 = (const float*)d_in[7];
  const float* b2 = (const float*)d_in[8];
  const float* wp_g = (const float*)d_in[9];
  const float* wp_b = (const float*)d_in[10];
  const float* wp_w = (const float*)d_in[11];
  const float* wp_bias = (const float*)d_in[12];
  const float* rp_g = (const float*)d_in[13];
  const float* rp_b = (const float*)d_in[14];
  const float* rp_w = (const float*)d_in[15];
  const float* rp_bias = (const float*)d_in[16];
  float* out = (float*)d_out;

  char* ws = (char*)d_ws;
  size_t off = 0;
  auto carve = [&](size_t bytes) -> void* {
    void* p = ws + off;
    off = (off + bytes + 255) & ~(size_t)255;
    return p;
  };

  __hip_bfloat16* w1t = (__hip_bfloat16*)carve((size_t)H_ * D_ * 2);  // [H, D]
  __hip_bfloat16* w2t = (__hip_bfloat16*)carve((size_t)D_ * H_ * 2);  // [D, H]
  __hip_bfloat16* aBf = (__hip_bfloat16*)carve((size_t)M_ * D_ * 2);  // LN1 out
  float* X = (float*)carve((size_t)M_ * D_ * 4);                      // FFN out
  int* flag = (int*)carve(256);
  int* present = (int*)carve((size_t)B_ * R_ * 4);
  float* routes = (float*)carve((size_t)B_ * R_ * D_ * 4);

  int G = 1;
  while (G < 16 && off + (size_t)M_ * (H_ / G) * 2 > ws_size) G <<= 1;
  const int Hg = H_ / G;
  __hip_bfloat16* hbuf = (__hip_bfloat16*)carve((size_t)M_ * Hg * 2);

  prep_kernel<<<513 + M_ / 8, 512, 0, stream>>>(
      tokens, mask_raw, ln1_g, ln1_b, w1, w2, aBf, w1t, w2t, flag);

  const int NC1 = Hg / 128;
  for (int g = 0; g < G; ++g) {
    gemm_bias_gelu_kernel<<<(M_ / 128) * NC1, 256, 0, stream>>>(
        aBf, w1t + (size_t)g * Hg * D_, b1 + (size_t)g * Hg, hbuf, D_, Hg, NC1);
    gemm_acc_kernel<<<(M_ / 256) * 4, 512, 0, stream>>>(
        hbuf, w2t + (size_t)g * Hg, b2, tokens, X, Hg, H_, (g == 0) ? 1 : 0);
  }

  route_pool_kernel<<<B_ * R_, 256, 0, stream>>>(
      X, route_ids, mask_raw, flag, wp_g, wp_b, wp_w, wp_bias,
      rp_g, rp_b, rp_w, rp_bias, routes, present, out);
}

// Round 8
// 350.963 us; speedup vs baseline: 1.6892x; 1.6892x over previous
//
#include <hip/hip_runtime.h>
#include <hip/hip_bf16.h>
#include <math.h>

// Problem constants (B=64, N=512, D=512, H=4D=2048, R=32 routes)
#define B_ 64
#define N_ 512
#define D_ 512
#define H_ 2048
#define R_ 32
#define M_ (B_ * N_)  // 32768 token rows

typedef __bf16 bf16x8 __attribute__((ext_vector_type(8)));
typedef float f32x4 __attribute__((ext_vector_type(4)));

__device__ __forceinline__ void async_ld16(const void* g, void* l) {
  __builtin_amdgcn_global_load_lds((__attribute__((address_space(1))) void*)g,
                                   (__attribute__((address_space(3))) void*)l,
                                   16, 0, 0);
}

// gelu via A&S 7.1.28 erf: 1 - 1/p^16, p = 1 + sum a_k x^k. |err| <= 3e-7.
// Polynomial + 4 squarings + 1 rcp — NO exp.
__device__ __forceinline__ float fast_gelu(float v) {
  const float s = v * 0.70710678118654752f;
  const float a = fabsf(s);
  float t = fmaf(a, 4.30638e-5f, 2.765672e-4f);
  t = fmaf(a, t, 1.520143e-4f);
  t = fmaf(a, t, 9.2705272e-3f);
  t = fmaf(a, t, 4.22820123e-2f);
  t = fmaf(a, t, 7.05230784e-2f);
  const float p = fmaf(a, t, 1.0f);
  float p16 = p * p;
  p16 = p16 * p16;
  p16 = p16 * p16;
  p16 = p16 * p16;
  const float er = 1.0f - __builtin_amdgcn_rcpf(p16);
  const float erfs = (s >= 0.f) ? er : -er;
  return 0.5f * v * (1.0f + erfs);
}

// ---------------------------------------------------------------------------
// PREP (one launch): bid 0 = mask dtype detect; bid 1..512 = w1/w2 transpose
// +cast; bid 513..4608 = LayerNorm rows -> bf16.
// ---------------------------------------------------------------------------
__global__ __launch_bounds__(512) void prep_kernel(
    const float* __restrict__ tokens, const void* __restrict__ mask_raw,
    const float* __restrict__ ln1_g, const float* __restrict__ ln1_b,
    const float* __restrict__ w1, const float* __restrict__ w2,
    __hip_bfloat16* __restrict__ aBf, __hip_bfloat16* __restrict__ w1t,
    __hip_bfloat16* __restrict__ w2t, int* __restrict__ flag) {
  const int bid = blockIdx.x;
  const int tid = threadIdx.x;
  if (bid == 0) {
    __shared__ int f;
    if (tid == 0) f = 0;
    __syncthreads();
    const uint4* p = (const uint4*)mask_raw;
    unsigned acc = 0;
    for (int k = tid; k < M_ / 16; k += 512) {
      const uint4 v = p[k];
      acc |= (v.x | v.y | v.z | v.w) & 0xFFFFFF00u;
    }
    if (acc) f = 1;  // benign race
    __syncthreads();
    if (tid == 0) flag[0] = f;
  } else if (bid <= 512) {
    __shared__ float tile[64][65];
    const int t = bid - 1;
    const float* src;
    __hip_bfloat16* dst;
    int R, C, cx, ry;
    if (t < 256) { src = w1; dst = w1t; R = 512; C = 2048; cx = t & 31; ry = t >> 5; }
    else { const int t2 = t - 256; src = w2; dst = w2t; R = 2048; C = 512; cx = t2 & 7; ry = t2 >> 3; }
    const int c0 = cx * 64, r0 = ry * 64;
    const int tx = tid & 63, ty = tid >> 6;
    for (int r = ty; r < 64; r += 8)
      tile[r][tx] = src[(size_t)(r0 + r) * C + c0 + tx];
    __syncthreads();
    for (int r = ty; r < 64; r += 8)
      dst[(size_t)(c0 + r) * R + r0 + tx] = __float2bfloat16(tile[tx][r]);
  } else {
    const int wv = tid >> 6, lane = tid & 63;
    const int row = (bid - 513) * 8 + wv;
    const float* p = tokens + (size_t)row * D_ + lane * 8;
    const float4 v0 = *(const float4*)p;
    const float4 v1 = *(const float4*)(p + 4);
    float s = v0.x + v0.y + v0.z + v0.w + v1.x + v1.y + v1.z + v1.w;
    float ss = v0.x * v0.x + v0.y * v0.y + v0.z * v0.z + v0.w * v0.w +
               v1.x * v1.x + v1.y * v1.y + v1.z * v1.z + v1.w * v1.w;
#pragma unroll
    for (int m = 32; m > 0; m >>= 1) {
      s += __shfl_xor(s, m);
      ss += __shfl_xor(ss, m);
    }
    const float mu = s * (1.0f / D_);
    const float rstd = rsqrtf(ss * (1.0f / D_) - mu * mu + 1e-5f);
    const float4 g0 = *(const float4*)(ln1_g + lane * 8);
    const float4 g1 = *(const float4*)(ln1_g + lane * 8 + 4);
    const float4 b0 = *(const float4*)(ln1_b + lane * 8);
    const float4 b1 = *(const float4*)(ln1_b + lane * 8 + 4);
    const float vv[8] = {v0.x, v0.y, v0.z, v0.w, v1.x, v1.y, v1.z, v1.w};
    const float gg[8] = {g0.x, g0.y, g0.z, g0.w, g1.x, g1.y, g1.z, g1.w};
    const float bb[8] = {b0.x, b0.y, b0.z, b0.w, b1.x, b1.y, b1.z, b1.w};
    union { __hip_bfloat16 h[8]; uint4 u; } pk;
#pragma unroll
    for (int t2 = 0; t2 < 8; ++t2)
      pk.h[t2] = __float2bfloat16((vv[t2] - mu) * rstd * gg[t2] + bb[t2]);
    *(uint4*)(aBf + (size_t)row * D_ + lane * 8) = pk.u;
  }
}

// ---------------------------------------------------------------------------
// GEMM1: C = gelu(A @ Bt^T + bias). 128x128 tile, BK=64 (32 MFMA/barrier).
// Conflict-free staging (global-side k-chunk XOR) + single-pass LDS-restage
// epilogue with packed bf16 cvt.
// ---------------------------------------------------------------------------
__global__ __launch_bounds__(256, 2) void gemm_bias_gelu_kernel(
    const __hip_bfloat16* __restrict__ A, const __hip_bfloat16* __restrict__ Bt,
    const float* __restrict__ bias, __hip_bfloat16* __restrict__ C,
    int K, int ldc, int NC) {
  __shared__ alignas(16) unsigned short SU[16384];  // 32 KB: As | Bs (128x64 each)
  unsigned short* As = SU;
  unsigned short* Bs = SU + 8192;
  const int tid = threadIdx.x;
  const int w = tid >> 6;
  const int lane = tid & 63;
  const int bid = blockIdx.x;
  const int rowT = (bid / (NC * 8)) * 8 + (bid & 7);
  const int colT = (bid >> 3) % NC;
  const int rowBase = rowT * 128;
  const int colBase = colT * 128;
  const int warpRow = w >> 1;
  const int warpCol = w & 1;
  const int q = lane >> 4;
  const int mr = lane & 15;
  const int srow8 = lane >> 3;
  const int sg8 = ((lane & 7) ^ srow8) * 8;
  const int mx7 = (mr & 7) * 8;

  f32x4 acc[4][4] = {};

  for (int k0 = 0; k0 < K; k0 += 64) {
    __syncthreads();
    {
      const __hip_bfloat16* Ak = A + (size_t)(rowBase + w * 32 + srow8) * K + k0 + sg8;
      const __hip_bfloat16* Bk = Bt + (size_t)(colBase + w * 32 + srow8) * K + k0 + sg8;
#pragma unroll
      for (int i = 0; i < 4; ++i) {
        async_ld16(Ak + (size_t)(i * 8) * K, (void*)&As[(w * 32 + i * 8) * 64]);
        async_ld16(Bk + (size_t)(i * 8) * K, (void*)&Bs[(w * 32 + i * 8) * 64]);
      }
    }
    __syncthreads();
#pragma unroll
    for (int s = 0; s < 2; ++s) {
      bf16x8 af[4], bf[4];
#pragma unroll
      for (int i = 0; i < 4; ++i)
        af[i] = *reinterpret_cast<const bf16x8*>(
            &As[(warpRow * 64 + i * 16 + mr) * 64 + (((s * 4 + q) * 8) ^ mx7)]);
#pragma unroll
      for (int j = 0; j < 4; ++j)
        bf[j] = *reinterpret_cast<const bf16x8*>(
            &Bs[(warpCol * 64 + j * 16 + mr) * 64 + (((s * 4 + q) * 8) ^ mx7)]);
#pragma unroll
      for (int i = 0; i < 4; ++i)
#pragma unroll
        for (int j = 0; j < 4; ++j)
          acc[i][j] = __builtin_amdgcn_mfma_f32_16x16x32_bf16(af[i], bf[j], acc[i][j], 0, 0, 0);
    }
  }

  // ---- single-pass epilogue: full 128x128 bf16 tile in 32 KB LDS ----
  __syncthreads();
  __hip_bfloat16* SB = (__hip_bfloat16*)SU;
#pragma unroll
  for (int j = 0; j < 4; ++j) {
    const int col = warpCol * 64 + j * 16 + mr;
    const float bv = bias[colBase + col];
    const int cl = col & 7;
    const int ch = col >> 3;
#pragma unroll
    for (int i = 0; i < 4; ++i) {
      float g[4];
#pragma unroll
      for (int r = 0; r < 4; ++r) g[r] = fast_gelu(acc[i][j][r] + bv);
      const __hip_bfloat162 p01 = __float22bfloat162_rn(make_float2(g[0], g[1]));
      const __hip_bfloat162 p23 = __float22bfloat162_rn(make_float2(g[2], g[3]));
      const int row0 = warpRow * 64 + i * 16 + q * 4;
      SB[(row0 + 0) * 128 + ((ch ^ ((row0 + 0) & 7)) << 3) + cl] = p01.x;
      SB[(row0 + 1) * 128 + ((ch ^ ((row0 + 1) & 7)) << 3) + cl] = p01.y;
      SB[(row0 + 2) * 128 + ((ch ^ ((row0 + 2) & 7)) << 3) + cl] = p23.x;
      SB[(row0 + 3) * 128 + ((ch ^ ((row0 + 3) & 7)) << 3) + cl] = p23.y;
    }
  }
  __syncthreads();
  const int lg = tid & 15, rsub = tid >> 4;
#pragma unroll
  for (int it = 0; it < 8; ++it) {
    const int m = it * 16 + rsub;
    const int slot = lg ^ (m & 7);
    const uint4 val = *(const uint4*)&SB[m * 128 + slot * 8];
    *(uint4*)&C[(size_t)(rowBase + m) * ldc + colBase + lg * 8] = val;
  }
}

// ---------------------------------------------------------------------------
// GEMM2: X = resid + bias + A @ Bt^T  (fp32 out w/ residual). BK=64,
// 256x128 tile, 512 threads (8 waves).
// ---------------------------------------------------------------------------
__global__ __launch_bounds__(512, 4) void gemm_acc_kernel(
    const __hip_bfloat16* __restrict__ A, const __hip_bfloat16* __restrict__ Bt,
    const float* __restrict__ bias, const float* __restrict__ resid,
    float* __restrict__ X, int K, int ldb, int first) {
  __shared__ alignas(16) unsigned short SU[24576];  // 48 KB: As 256x64 | Bs 128x64
  unsigned short* As = SU;
  unsigned short* Bs = SU + 16384;
  const int tid = threadIdx.x;
  const int w = tid >> 6;
  const int lane = tid & 63;
  const int bid = blockIdx.x;
  const int NC = 4;
  const int rowT = (bid / (NC * 8)) * 8 + (bid & 7);
  const int colT = (bid >> 3) % NC;
  const int rowBase = rowT * 256;
  const int colBase = colT * 128;
  const int warpRow = w >> 1;
  const int warpCol = w & 1;
  const int q = lane >> 4;
  const int mr = lane & 15;
  const int srow8 = lane >> 3;
  const int sg8 = ((lane & 7) ^ srow8) * 8;
  const int mx7 = (mr & 7) * 8;

  f32x4 acc[4][4] = {};

  for (int k0 = 0; k0 < K; k0 += 64) {
    __syncthreads();
    {
      const __hip_bfloat16* Ak = A + (size_t)(rowBase + w * 32 + srow8) * K + k0 + sg8;
#pragma unroll
      for (int i = 0; i < 4; ++i)
        async_ld16(Ak + (size_t)(i * 8) * K, (void*)&As[(w * 32 + i * 8) * 64]);
      const __hip_bfloat16* Bk = Bt + (size_t)(colBase + w * 16 + srow8) * ldb + k0 + sg8;
#pragma unroll
      for (int i = 0; i < 2; ++i)
        async_ld16(Bk + (size_t)(i * 8) * ldb, (void*)&Bs[(w * 16 + i * 8) * 64]);
    }
    __syncthreads();
#pragma unroll
    for (int s = 0; s < 2; ++s) {
      bf16x8 af[4], bf[4];
#pragma unroll
      for (int i = 0; i < 4; ++i)
        af[i] = *reinterpret_cast<const bf16x8*>(
            &As[(warpRow * 64 + i * 16 + mr) * 64 + (((s * 4 + q) * 8) ^ mx7)]);
#pragma unroll
      for (int j = 0; j < 4; ++j)
        bf[j] = *reinterpret_cast<const bf16x8*>(
            &Bs[(warpCol * 64 + j * 16 + mr) * 64 + (((s * 4 + q) * 8) ^ mx7)]);
#pragma unroll
      for (int i = 0; i < 4; ++i)
#pragma unroll
        for (int j = 0; j < 4; ++j)
          acc[i][j] = __builtin_amdgcn_mfma_f32_16x16x32_bf16(af[i], bf[j], acc[i][j], 0, 0, 0);
    }
  }

#pragma unroll
  for (int j = 0; j < 4; ++j) {
    const int n = colBase + warpCol * 64 + j * 16 + mr;
    const float bv = bias[n];
#pragma unroll
    for (int i = 0; i < 4; ++i) {
#pragma unroll
      for (int r = 0; r < 4; ++r) {
        const int m = rowBase + warpRow * 64 + i * 16 + q * 4 + r;
        const size_t idx = (size_t)m * N_ + n;
        const float base = first ? (resid[idx] + bv) : X[idx];
        X[idx] = base + acc[i][j][r];
      }
    }
  }
}

// ---------------------------------------------------------------------------
// Fused per-(b,route) pool: select tokens, LN+dot logits, masked softmax,
// weighted sum -> routes. (No LDS row staging — second X read is L1/L2-hit;
// no cross-block sync — both were measured regressions.)
// ---------------------------------------------------------------------------
__global__ __launch_bounds__(256) void route_pool_kernel(
    const float* __restrict__ X, const int* __restrict__ route_ids,
    const void* __restrict__ mask_raw, const int* __restrict__ flag,
    const float* __restrict__ gw, const float* __restrict__ gb,
    const float* __restrict__ ww, const float* __restrict__ wbias,
    float* __restrict__ routes, int* __restrict__ present) {
  const int b = blockIdx.x >> 5;
  const int r = blockIdx.x & 31;
  const int tid = threadIdx.x;
  __shared__ int cnt;
  __shared__ int ls[N_];
  __shared__ float lw[N_];
  if (tid == 0) cnt = 0;
  __syncthreads();
  const int fl = flag[0];
  for (int n = tid; n < N_; n += 256) {
    const int mk = fl ? (int)((const unsigned char*)mask_raw)[b * N_ + n]
                      : ((const int*)mask_raw)[b * N_ + n];
    if (route_ids[n] == r && mk != 0) {
      int p = atomicAdd(&cnt, 1);
      ls[p] = n;
    }
  }
  __syncthreads();
  const int c = cnt;
  const int wv = tid >> 6, lane = tid & 63;
  for (int t = wv; t < c; t += 4) {
    const float* p = X + ((size_t)b * N_ + ls[t]) * D_ + lane * 8;
    const float4 v0 = *(const float4*)p;
    const float4 v1 = *(const float4*)(p + 4);
    float s = v0.x + v0.y + v0.z + v0.w + v1.x + v1.y + v1.z + v1.w;
    float ss = v0.x * v0.x + v0.y * v0.y + v0.z * v0.z + v0.w * v0.w +
               v1.x * v1.x + v1.y * v1.y + v1.z * v1.z + v1.w * v1.w;
#pragma unroll
    for (int m = 32; m > 0; m >>= 1) {
      s += __shfl_xor(s, m);
      ss += __shfl_xor(ss, m);
    }
    const float mu = s * (1.0f / D_);
    const float rstd = rsqrtf(ss * (1.0f / D_) - mu * mu + 1e-5f);
    const float4 g0 = *(const float4*)(gw + lane * 8);
    const float4 g1 = *(const float4*)(gw + lane * 8 + 4);
    const float4 b0 = *(const float4*)(gb + lane * 8);
    const float4 b1v = *(const float4*)(gb + lane * 8 + 4);
    const float4 w0 = *(const float4*)(ww + lane * 8);
    const float4 w1v = *(const float4*)(ww + lane * 8 + 4);
    const float vv[8] = {v0.x, v0.y, v0.z, v0.w, v1.x, v1.y, v1.z, v1.w};
    const float gg[8] = {g0.x, g0.y, g0.z, g0.w, g1.x, g1.y, g1.z, g1.w};
    const float bb[8] = {b0.x, b0.y, b0.z, b0.w, b1v.x, b1v.y, b1v.z, b1v.w};
    const float wwv[8] = {w0.x, w0.y, w0.z, w0.w, w1v.x, w1v.y, w1v.z, w1v.w};
    float a = 0.f;
#pragma unroll
    for (int t2 = 0; t2 < 8; ++t2) a += ((vv[t2] - mu) * rstd * gg[t2] + bb[t2]) * wwv[t2];
#pragma unroll
    for (int m = 32; m > 0; m >>= 1) a += __shfl_xor(a, m);
    if (lane == 0) lw[t] = a + wbias[0];
  }
  __syncthreads();
  if (tid == 0 && c > 0) {
    float mx = -1e30f;
    for (int i = 0; i < c; ++i) mx = fmaxf(mx, lw[i]);
    float sm = 0.f;
    for (int i = 0; i < c; ++i) {
      const float e = __expf(lw[i] - mx);
      lw[i] = e;
      sm += e;
    }
    const float inv = 1.0f / sm;
    for (int i = 0; i < c; ++i) lw[i] *= inv;
  }
  __syncthreads();
  float a0 = 0.f, a1 = 0.f;
  for (int i = 0; i < c; ++i) {
    const float* xr = X + ((size_t)b * N_ + ls[i]) * D_;
    const float wgt = lw[i];
    a0 += wgt * xr[tid];
    a1 += wgt * xr[tid + 256];
  }
  float* outp = routes + ((size_t)b * R_ + r) * D_;
  outp[tid] = a0;
  outp[tid + 256] = a1;
  if (tid == 0) present[b * R_ + r] = (c > 0) ? 1 : 0;
}

// ---------------------------------------------------------------------------
// Final pool over routes (one block of 512 per batch)
// ---------------------------------------------------------------------------
__global__ __launch_bounds__(512) void final_pool_kernel(
    const float* __restrict__ routes, const int* __restrict__ present,
    const float* __restrict__ gw, const float* __restrict__ gb,
    const float* __restrict__ ww, const float* __restrict__ wbias,
    float* __restrict__ out) {
  const int b = blockIdx.x;
  const int wv = threadIdx.x >> 6, lane = threadIdx.x & 63;
  __shared__ float srw[R_];
  __shared__ float srl[R_];
  for (int r = wv; r < R_; r += 8) {
    const float* p = routes + ((size_t)b * R_ + r) * D_ + lane * 8;
    const float4 v0 = *(const float4*)p;
    const float4 v1 = *(const float4*)(p + 4);
    float s = v0.x + v0.y + v0.z + v0.w + v1.x + v1.y + v1.z + v1.w;
    float ss = v0.x * v0.x + v0.y * v0.y + v0.z * v0.z + v0.w * v0.w +
               v1.x * v1.x + v1.y * v1.y + v1.z * v1.z + v1.w * v1.w;
#pragma unroll
    for (int m = 32; m > 0; m >>= 1) {
      s += __shfl_xor(s, m);
      ss += __shfl_xor(ss, m);
    }
    const float mu = s * (1.0f / D_);
    const float rstd = rsqrtf(ss * (1.0f / D_) - mu * mu + 1e-5f);
    const float4 g0 = *(const float4*)(gw + lane * 8);
    const float4 g1 = *(const float4*)(gw + lane * 8 + 4);
    const float4 b0 = *(const float4*)(gb + lane * 8);
    const float4 b1v = *(const float4*)(gb + lane * 8 + 4);
    const float4 w0 = *(const float4*)(ww + lane * 8);
    const float4 w1v = *(const float4*)(ww + lane * 8 + 4);
    const float vv[8] = {v0.x, v0.y, v0.z, v0.w, v1.x, v1.y, v1.z, v1.w};
    const float gg[8] = {g0.x, g0.y, g0.z, g0.w, g1.x, g1.y, g1.z, g1.w};
    const float bb[8] = {b0.x, b0.y, b0.z, b0.w, b1v.x, b1v.y, b1v.z, b1v.w};
    const float wwv[8] = {w0.x, w0.y, w0.z, w0.w, w1v.x, w1v.y, w1v.z, w1v.w};
    float a = 0.f;
#pragma unroll
    for (int t = 0; t < 8; ++t) a += ((vv[t] - mu) * rstd * gg[t] + bb[t]) * wwv[t];
#pragma unroll
    for (int m = 32; m > 0; m >>= 1) a += __shfl_xor(a, m);
    if (lane == 0) srl[r] = a + wbias[0];
  }
  __syncthreads();
  if (threadIdx.x == 0) {
    float mx = -1e30f;
    for (int r = 0; r < R_; ++r)
      if (present[b * R_ + r]) mx = fmaxf(mx, srl[r]);
    float sm = 0.f;
    for (int r = 0; r < R_; ++r) {
      const float e = present[b * R_ + r] ? __expf(srl[r] - mx) : 0.f;
      srw[r] = e;
      sm += e;
    }
    const float inv = (sm > 0.f) ? 1.0f / sm : 0.f;
    for (int r = 0; r < R_; ++r) srw[r] *= inv;
  }
  __syncthreads();
  const int d = threadIdx.x;
  float a = 0.f;
  for (int r = 0; r < R_; ++r) a += srw[r] * routes[((size_t)b * R_ + r) * D_ + d];
  out[(size_t)b * D_ + d] = a;
}

// ---------------------------------------------------------------------------
extern "C" void kernel_launch(void* const* d_in, const int* in_sizes, int n_in,
                              void* d_out, int out_size, void* d_ws, size_t ws_size,
                              hipStream_t stream) {
  const float* tokens = (const float*)d_in[0];
  const void* mask_raw = d_in[1];
  const int* route_ids = (const int*)d_in[2];
  const float* ln1_g = (const float*)d_in[3];
  const float* ln1_b = (const float*)d_in[4];
  const float* w1 = (const float*)d_in[5];
  const float* b1 = (const float*)d_in[6];
  const float* w2 = (const float*)d_in[7];
  const float* b2 = (const float*)d_in[8];
  const float* wp_g = (const float*)d_in[9];
  const float* wp_b = (const float*)d_in[10];
  const float* wp_w = (const float*)d_in[11];
  const float* wp_bias = (const float*)d_in[12];
  const float* rp_g = (const float*)d_in[13];
  const float* rp_b = (const float*)d_in[14];
  const float* rp_w = (const float*)d_in[15];
  const float* rp_bias = (const float*)d_in[16];
  float* out = (float*)d_out;

  char* ws = (char*)d_ws;
  size_t off = 0;
  auto carve = [&](size_t bytes) -> void* {
    void* p = ws + off;
    off = (off + bytes + 255) & ~(size_t)255;
    return p;
  };

  __hip_bfloat16* w1t = (__hip_bfloat16*)carve((size_t)H_ * D_ * 2);  // [H, D]
  __hip_bfloat16* w2t = (__hip_bfloat16*)carve((size_t)D_ * H_ * 2);  // [D, H]
  __hip_bfloat16* aBf = (__hip_bfloat16*)carve((size_t)M_ * D_ * 2);  // LN1 out
  float* X = (float*)carve((size_t)M_ * D_ * 4);                      // FFN out
  int* flag = (int*)carve(256);
  int* present = (int*)carve((size_t)B_ * R_ * 4);
  float* routes = (float*)carve((size_t)B_ * R_ * D_ * 4);

  int G = 1;
  while (G < 16 && off + (size_t)M_ * (H_ / G) * 2 > ws_size) G <<= 1;
  const int Hg = H_ / G;
  __hip_bfloat16* hbuf = (__hip_bfloat16*)carve((size_t)M_ * Hg * 2);

  prep_kernel<<<513 + M_ / 8, 512, 0, stream>>>(
      tokens, mask_raw, ln1_g, ln1_b, w1, w2, aBf, w1t, w2t, flag);

  const int NC1 = Hg / 128;
  for (int g = 0; g < G; ++g) {
    gemm_bias_gelu_kernel<<<(M_ / 128) * NC1, 256, 0, stream>>>(
        aBf, w1t + (size_t)g * Hg * D_, b1 + (size_t)g * Hg, hbuf, D_, Hg, NC1);
    gemm_acc_kernel<<<(M_ / 256) * 4, 512, 0, stream>>>(
        hbuf, w2t + (size_t)g * Hg, b2, tokens, X, Hg, H_, (g == 0) ? 1 : 0);
  }

  route_pool_kernel<<<B_ * R_, 256, 0, stream>>>(
      X, route_ids, mask_raw, flag, wp_g, wp_b, wp_w, wp_bias, routes, present);
  final_pool_kernel<<<B_, 512, 0, stream>>>(routes, present, rp_g, rp_b, rp_w, rp_bias, out);
}

// Round 9
// 349.117 us; speedup vs baseline: 1.6981x; 1.0053x over previous
//
#include <hip/hip_runtime.h>
#include <hip/hip_bf16.h>
#include <math.h>

// Problem constants (B=64, N=512, D=512, H=4D=2048, R=32 routes)
#define B_ 64
#define N_ 512
#define D_ 512
#define H_ 2048
#define R_ 32
#define M_ (B_ * N_)  // 32768 token rows

typedef __bf16 bf16x8 __attribute__((ext_vector_type(8)));
typedef float f32x4 __attribute__((ext_vector_type(4)));

__device__ __forceinline__ void async_ld16(const void* g, void* l) {
  __builtin_amdgcn_global_load_lds((__attribute__((address_space(1))) void*)g,
                                   (__attribute__((address_space(3))) void*)l,
                                   16, 0, 0);
}

// gelu via A&S 7.1.28 erf: 1 - 1/p^16. |err| <= 3e-7. No exp.
__device__ __forceinline__ float fast_gelu(float v) {
  const float s = v * 0.70710678118654752f;
  const float a = fabsf(s);
  float t = fmaf(a, 4.30638e-5f, 2.765672e-4f);
  t = fmaf(a, t, 1.520143e-4f);
  t = fmaf(a, t, 9.2705272e-3f);
  t = fmaf(a, t, 4.22820123e-2f);
  t = fmaf(a, t, 7.05230784e-2f);
  const float p = fmaf(a, t, 1.0f);
  float p16 = p * p;
  p16 = p16 * p16;
  p16 = p16 * p16;
  p16 = p16 * p16;
  const float er = 1.0f - __builtin_amdgcn_rcpf(p16);
  const float erfs = (s >= 0.f) ? er : -er;
  return 0.5f * v * (1.0f + erfs);
}

// ---------------------------------------------------------------------------
// PREP: bid 0 = mask detect + S1/S2 scalars + zero logit-stat buffers;
// bid 1..512 = w1/w2 transpose+cast; bid 513..4608 = LN rows -> bf16.
// ---------------------------------------------------------------------------
__global__ __launch_bounds__(512) void prep_kernel(
    const float* __restrict__ tokens, const void* __restrict__ mask_raw,
    const float* __restrict__ ln1_g, const float* __restrict__ ln1_b,
    const float* __restrict__ w1, const float* __restrict__ w2,
    const float* __restrict__ wp_g, const float* __restrict__ wp_b,
    const float* __restrict__ wp_w,
    __hip_bfloat16* __restrict__ aBf, __hip_bfloat16* __restrict__ w1t,
    __hip_bfloat16* __restrict__ w2t, int* __restrict__ flag,
    float* __restrict__ scr, float* __restrict__ stats) {
  const int bid = blockIdx.x;
  const int tid = threadIdx.x;
  if (bid == 0) {
    __shared__ int f;
    __shared__ float red[2][8];
    if (tid == 0) f = 0;
    __syncthreads();
    const uint4* p = (const uint4*)mask_raw;
    unsigned acc = 0;
    for (int k = tid; k < M_ / 16; k += 512) {
      const uint4 v = p[k];
      acc |= (v.x | v.y | v.z | v.w) & 0xFFFFFF00u;
    }
    if (acc) f = 1;  // benign race
    // S1 = sum(g*w), S2 = sum(b*w) over D=512 (one elem per thread)
    const int wv = tid >> 6, lane = tid & 63;
    float gw = wp_g[tid] * wp_w[tid];
    float bw = wp_b[tid] * wp_w[tid];
#pragma unroll
    for (int m = 32; m > 0; m >>= 1) {
      gw += __shfl_xor(gw, m);
      bw += __shfl_xor(bw, m);
    }
    if (lane == 0) { red[0][wv] = gw; red[1][wv] = bw; }
    // zero the per-row logit stat accumulators (3 * M floats)
    for (int k = tid; k < 3 * M_; k += 512) stats[k] = 0.f;
    __syncthreads();
    if (tid == 0) {
      flag[0] = f;
      float s1 = 0.f, s2 = 0.f;
      for (int i = 0; i < 8; ++i) { s1 += red[0][i]; s2 += red[1][i]; }
      scr[0] = s1;
      scr[1] = s2;
    }
  } else if (bid <= 512) {
    __shared__ float tile[64][65];
    const int t = bid - 1;
    const float* src;
    __hip_bfloat16* dst;
    int R, C, cx, ry;
    if (t < 256) { src = w1; dst = w1t; R = 512; C = 2048; cx = t & 31; ry = t >> 5; }
    else { const int t2 = t - 256; src = w2; dst = w2t; R = 2048; C = 512; cx = t2 & 7; ry = t2 >> 3; }
    const int c0 = cx * 64, r0 = ry * 64;
    const int tx = tid & 63, ty = tid >> 6;
    for (int r = ty; r < 64; r += 8)
      tile[r][tx] = src[(size_t)(r0 + r) * C + c0 + tx];
    __syncthreads();
    for (int r = ty; r < 64; r += 8)
      dst[(size_t)(c0 + r) * R + r0 + tx] = __float2bfloat16(tile[tx][r]);
  } else {
    const int wv = tid >> 6, lane = tid & 63;
    const int row = (bid - 513) * 8 + wv;
    const float* p = tokens + (size_t)row * D_ + lane * 8;
    const float4 v0 = *(const float4*)p;
    const float4 v1 = *(const float4*)(p + 4);
    float s = v0.x + v0.y + v0.z + v0.w + v1.x + v1.y + v1.z + v1.w;
    float ss = v0.x * v0.x + v0.y * v0.y + v0.z * v0.z + v0.w * v0.w +
               v1.x * v1.x + v1.y * v1.y + v1.z * v1.z + v1.w * v1.w;
#pragma unroll
    for (int m = 32; m > 0; m >>= 1) {
      s += __shfl_xor(s, m);
      ss += __shfl_xor(ss, m);
    }
    const float mu = s * (1.0f / D_);
    const float rstd = rsqrtf(ss * (1.0f / D_) - mu * mu + 1e-5f);
    const float4 g0 = *(const float4*)(ln1_g + lane * 8);
    const float4 g1 = *(const float4*)(ln1_g + lane * 8 + 4);
    const float4 b0 = *(const float4*)(ln1_b + lane * 8);
    const float4 b1 = *(const float4*)(ln1_b + lane * 8 + 4);
    const float vv[8] = {v0.x, v0.y, v0.z, v0.w, v1.x, v1.y, v1.z, v1.w};
    const float gg[8] = {g0.x, g0.y, g0.z, g0.w, g1.x, g1.y, g1.z, g1.w};
    const float bb[8] = {b0.x, b0.y, b0.z, b0.w, b1.x, b1.y, b1.z, b1.w};
    union { __hip_bfloat16 h[8]; uint4 u; } pk;
#pragma unroll
    for (int t2 = 0; t2 < 8; ++t2)
      pk.h[t2] = __float2bfloat16((vv[t2] - mu) * rstd * gg[t2] + bb[t2]);
    *(uint4*)(aBf + (size_t)row * D_ + lane * 8) = pk.u;
  }
}

// ---------------------------------------------------------------------------
// GEMM1: C = gelu(A @ Bt^T + bias). 128x128 tile, BK=64 (32 MFMA/barrier).
// Conflict-free staging + single-pass LDS-restage epilogue, packed bf16 cvt.
// ---------------------------------------------------------------------------
__global__ __launch_bounds__(256, 2) void gemm_bias_gelu_kernel(
    const __hip_bfloat16* __restrict__ A, const __hip_bfloat16* __restrict__ Bt,
    const float* __restrict__ bias, __hip_bfloat16* __restrict__ C,
    int K, int ldc, int NC) {
  __shared__ alignas(16) unsigned short SU[16384];  // 32 KB: As | Bs (128x64 each)
  unsigned short* As = SU;
  unsigned short* Bs = SU + 8192;
  const int tid = threadIdx.x;
  const int w = tid >> 6;
  const int lane = tid & 63;
  const int bid = blockIdx.x;
  const int rowT = (bid / (NC * 8)) * 8 + (bid & 7);
  const int colT = (bid >> 3) % NC;
  const int rowBase = rowT * 128;
  const int colBase = colT * 128;
  const int warpRow = w >> 1;
  const int warpCol = w & 1;
  const int q = lane >> 4;
  const int mr = lane & 15;
  const int srow8 = lane >> 3;
  const int sg8 = ((lane & 7) ^ srow8) * 8;
  const int mx7 = (mr & 7) * 8;

  f32x4 acc[4][4] = {};

  for (int k0 = 0; k0 < K; k0 += 64) {
    __syncthreads();
    {
      const __hip_bfloat16* Ak = A + (size_t)(rowBase + w * 32 + srow8) * K + k0 + sg8;
      const __hip_bfloat16* Bk = Bt + (size_t)(colBase + w * 32 + srow8) * K + k0 + sg8;
#pragma unroll
      for (int i = 0; i < 4; ++i) {
        async_ld16(Ak + (size_t)(i * 8) * K, (void*)&As[(w * 32 + i * 8) * 64]);
        async_ld16(Bk + (size_t)(i * 8) * K, (void*)&Bs[(w * 32 + i * 8) * 64]);
      }
    }
    __syncthreads();
#pragma unroll
    for (int s = 0; s < 2; ++s) {
      bf16x8 af[4], bf[4];
#pragma unroll
      for (int i = 0; i < 4; ++i)
        af[i] = *reinterpret_cast<const bf16x8*>(
            &As[(warpRow * 64 + i * 16 + mr) * 64 + (((s * 4 + q) * 8) ^ mx7)]);
#pragma unroll
      for (int j = 0; j < 4; ++j)
        bf[j] = *reinterpret_cast<const bf16x8*>(
            &Bs[(warpCol * 64 + j * 16 + mr) * 64 + (((s * 4 + q) * 8) ^ mx7)]);
#pragma unroll
      for (int i = 0; i < 4; ++i)
#pragma unroll
        for (int j = 0; j < 4; ++j)
          acc[i][j] = __builtin_amdgcn_mfma_f32_16x16x32_bf16(af[i], bf[j], acc[i][j], 0, 0, 0);
    }
  }

  __syncthreads();
  __hip_bfloat16* SB = (__hip_bfloat16*)SU;
#pragma unroll
  for (int j = 0; j < 4; ++j) {
    const int col = warpCol * 64 + j * 16 + mr;
    const float bv = bias[colBase + col];
    const int cl = col & 7;
    const int ch = col >> 3;
#pragma unroll
    for (int i = 0; i < 4; ++i) {
      float g[4];
#pragma unroll
      for (int r = 0; r < 4; ++r) g[r] = fast_gelu(acc[i][j][r] + bv);
      const __hip_bfloat162 p01 = __float22bfloat162_rn(make_float2(g[0], g[1]));
      const __hip_bfloat162 p23 = __float22bfloat162_rn(make_float2(g[2], g[3]));
      const int row0 = warpRow * 64 + i * 16 + q * 4;
      SB[(row0 + 0) * 128 + ((ch ^ ((row0 + 0) & 7)) << 3) + cl] = p01.x;
      SB[(row0 + 1) * 128 + ((ch ^ ((row0 + 1) & 7)) << 3) + cl] = p01.y;
      SB[(row0 + 2) * 128 + ((ch ^ ((row0 + 2) & 7)) << 3) + cl] = p23.x;
      SB[(row0 + 3) * 128 + ((ch ^ ((row0 + 3) & 7)) << 3) + cl] = p23.y;
    }
  }
  __syncthreads();
  const int lg = tid & 15, rsub = tid >> 4;
#pragma unroll
  for (int it = 0; it < 8; ++it) {
    const int m = it * 16 + rsub;
    const int slot = lg ^ (m & 7);
    const uint4 val = *(const uint4*)&SB[m * 128 + slot * 8];
    *(uint4*)&C[(size_t)(rowBase + m) * ldc + colBase + lg * 8] = val;
  }
}

// ---------------------------------------------------------------------------
// GEMM2: X = resid + bias + A @ Bt^T, plus per-row logit-stat accumulation
// (Sx, Sxx, P = sum x*(wp_g.wp_w)) via lane-group shuffle + atomicAdd.
// BK=64, 256x128 tile, 512 threads.
// ---------------------------------------------------------------------------
__global__ __launch_bounds__(512, 4) void gemm_acc_kernel(
    const __hip_bfloat16* __restrict__ A, const __hip_bfloat16* __restrict__ Bt,
    const float* __restrict__ bias, const float* __restrict__ resid,
    float* __restrict__ X, const float* __restrict__ wp_g,
    const float* __restrict__ wp_w, float* __restrict__ stats,
    int K, int ldb, int first, int stats_on) {
  __shared__ alignas(16) unsigned short SU[24576];  // 48 KB: As 256x64 | Bs 128x64
  unsigned short* As = SU;
  unsigned short* Bs = SU + 16384;
  const int tid = threadIdx.x;
  const int w = tid >> 6;
  const int lane = tid & 63;
  const int bid = blockIdx.x;
  const int NC = 4;
  const int rowT = (bid / (NC * 8)) * 8 + (bid & 7);
  const int colT = (bid >> 3) % NC;
  const int rowBase = rowT * 256;
  const int colBase = colT * 128;
  const int warpRow = w >> 1;
  const int warpCol = w & 1;
  const int q = lane >> 4;
  const int mr = lane & 15;
  const int srow8 = lane >> 3;
  const int sg8 = ((lane & 7) ^ srow8) * 8;
  const int mx7 = (mr & 7) * 8;

  f32x4 acc[4][4] = {};

  for (int k0 = 0; k0 < K; k0 += 64) {
    __syncthreads();
    {
      const __hip_bfloat16* Ak = A + (size_t)(rowBase + w * 32 + srow8) * K + k0 + sg8;
#pragma unroll
      for (int i = 0; i < 4; ++i)
        async_ld16(Ak + (size_t)(i * 8) * K, (void*)&As[(w * 32 + i * 8) * 64]);
      const __hip_bfloat16* Bk = Bt + (size_t)(colBase + w * 16 + srow8) * ldb + k0 + sg8;
#pragma unroll
      for (int i = 0; i < 2; ++i)
        async_ld16(Bk + (size_t)(i * 8) * ldb, (void*)&Bs[(w * 16 + i * 8) * 64]);
    }
    __syncthreads();
#pragma unroll
    for (int s = 0; s < 2; ++s) {
      bf16x8 af[4], bf[4];
#pragma unroll
      for (int i = 0; i < 4; ++i)
        af[i] = *reinterpret_cast<const bf16x8*>(
            &As[(warpRow * 64 + i * 16 + mr) * 64 + (((s * 4 + q) * 8) ^ mx7)]);
#pragma unroll
      for (int j = 0; j < 4; ++j)
        bf[j] = *reinterpret_cast<const bf16x8*>(
            &Bs[(warpCol * 64 + j * 16 + mr) * 64 + (((s * 4 + q) * 8) ^ mx7)]);
#pragma unroll
      for (int i = 0; i < 4; ++i)
#pragma unroll
        for (int j = 0; j < 4; ++j)
          acc[i][j] = __builtin_amdgcn_mfma_f32_16x16x32_bf16(af[i], bf[j], acc[i][j], 0, 0, 0);
    }
  }

  float* Sx = stats;
  float* Sxx = stats + M_;
  float* Pd = stats + 2 * M_;
  float bv[4], gwv[4];
#pragma unroll
  for (int j = 0; j < 4; ++j) {
    const int n = colBase + warpCol * 64 + j * 16 + mr;
    bv[j] = bias[n];
    gwv[j] = stats_on ? (wp_g[n] * wp_w[n]) : 0.f;
  }
#pragma unroll
  for (int i = 0; i < 4; ++i) {
#pragma unroll
    for (int r = 0; r < 4; ++r) {
      const int m = rowBase + warpRow * 64 + i * 16 + q * 4 + r;
      float sx = 0.f, sxx = 0.f, sp = 0.f;
#pragma unroll
      for (int j = 0; j < 4; ++j) {
        const int n = colBase + warpCol * 64 + j * 16 + mr;
        const size_t idx = (size_t)m * N_ + n;
        const float base = first ? (resid[idx] + bv[j]) : X[idx];
        const float xv = base + acc[i][j][r];
        X[idx] = xv;
        sx += xv;
        sxx += xv * xv;
        sp += xv * gwv[j];
      }
      if (stats_on) {
#pragma unroll
        for (int mm = 1; mm < 16; mm <<= 1) {
          sx += __shfl_xor(sx, mm);
          sxx += __shfl_xor(sxx, mm);
          sp += __shfl_xor(sp, mm);
        }
        if (mr == 0) {
          atomicAdd(&Sx[m], sx);
          atomicAdd(&Sxx[m], sxx);
          atomicAdd(&Pd[m], sp);
        }
      }
    }
  }
}

// ---------------------------------------------------------------------------
// Per-(b,route) pool: select tokens, logits from precomputed row stats
// (lw = rstd*(P - mu*S1) + S2 + bias), masked softmax, weighted sum -> routes.
// ---------------------------------------------------------------------------
__global__ __launch_bounds__(256) void route_pool_kernel(
    const float* __restrict__ X, const int* __restrict__ route_ids,
    const void* __restrict__ mask_raw, const int* __restrict__ flag,
    const float* __restrict__ scr, const float* __restrict__ stats,
    const float* __restrict__ wbias,
    float* __restrict__ routes, int* __restrict__ present) {
  const int b = blockIdx.x >> 5;
  const int r = blockIdx.x & 31;
  const int tid = threadIdx.x;
  __shared__ int cnt;
  __shared__ int ls[N_];
  __shared__ float lw[N_];
  if (tid == 0) cnt = 0;
  __syncthreads();
  const int fl = flag[0];
  for (int n = tid; n < N_; n += 256) {
    const int mk = fl ? (int)((const unsigned char*)mask_raw)[b * N_ + n]
                      : ((const int*)mask_raw)[b * N_ + n];
    if (route_ids[n] == r && mk != 0) {
      int p = atomicAdd(&cnt, 1);
      ls[p] = n;
    }
  }
  __syncthreads();
  const int c = cnt;
  // logits from stats (one thread per selected token)
  const float S1 = scr[0], S2 = scr[1];
  const float* Sx = stats;
  const float* Sxx = stats + M_;
  const float* Pd = stats + 2 * M_;
  for (int t = tid; t < c; t += 256) {
    const int row = b * N_ + ls[t];
    const float mu = Sx[row] * (1.0f / D_);
    const float var = Sxx[row] * (1.0f / D_) - mu * mu;
    const float rstd = rsqrtf(var + 1e-5f);
    lw[t] = rstd * (Pd[row] - mu * S1) + S2 + wbias[0];
  }
  __syncthreads();
  if (tid == 0 && c > 0) {
    float mx = -1e30f;
    for (int i = 0; i < c; ++i) mx = fmaxf(mx, lw[i]);
    float sm = 0.f;
    for (int i = 0; i < c; ++i) {
      const float e = __expf(lw[i] - mx);
      lw[i] = e;
      sm += e;
    }
    const float inv = 1.0f / sm;
    for (int i = 0; i < c; ++i) lw[i] *= inv;
  }
  __syncthreads();
  float a0 = 0.f, a1 = 0.f;
  for (int i = 0; i < c; ++i) {
    const float* xr = X + ((size_t)b * N_ + ls[i]) * D_;
    const float wgt = lw[i];
    a0 += wgt * xr[tid];
    a1 += wgt * xr[tid + 256];
  }
  float* outp = routes + ((size_t)b * R_ + r) * D_;
  outp[tid] = a0;
  outp[tid + 256] = a1;
  if (tid == 0) present[b * R_ + r] = (c > 0) ? 1 : 0;
}

// ---------------------------------------------------------------------------
// Final pool over routes (one block of 512 per batch)
// ---------------------------------------------------------------------------
__global__ __launch_bounds__(512) void final_pool_kernel(
    const float* __restrict__ routes, const int* __restrict__ present,
    const float* __restrict__ gw, const float* __restrict__ gb,
    const float* __restrict__ ww, const float* __restrict__ wbias,
    float* __restrict__ out) {
  const int b = blockIdx.x;
  const int wv = threadIdx.x >> 6, lane = threadIdx.x & 63;
  __shared__ float srw[R_];
  __shared__ float srl[R_];
  for (int r = wv; r < R_; r += 8) {
    const float* p = routes + ((size_t)b * R_ + r) * D_ + lane * 8;
    const float4 v0 = *(const float4*)p;
    const float4 v1 = *(const float4*)(p + 4);
    float s = v0.x + v0.y + v0.z + v0.w + v1.x + v1.y + v1.z + v1.w;
    float ss = v0.x * v0.x + v0.y * v0.y + v0.z * v0.z + v0.w * v0.w +
               v1.x * v1.x + v1.y * v1.y + v1.z * v1.z + v1.w * v1.w;
#pragma unroll
    for (int m = 32; m > 0; m >>= 1) {
      s += __shfl_xor(s, m);
      ss += __shfl_xor(ss, m);
    }
    const float mu = s * (1.0f / D_);
    const float rstd = rsqrtf(ss * (1.0f / D_) - mu * mu + 1e-5f);
    const float4 g0 = *(const float4*)(gw + lane * 8);
    const float4 g1 = *(const float4*)(gw + lane * 8 + 4);
    const float4 b0 = *(const float4*)(gb + lane * 8);
    const float4 b1v = *(const float4*)(gb + lane * 8 + 4);
    const float4 w0 = *(const float4*)(ww + lane * 8);
    const float4 w1v = *(const float4*)(ww + lane * 8 + 4);
    const float vv[8] = {v0.x, v0.y, v0.z, v0.w, v1.x, v1.y, v1.z, v1.w};
    const float gg[8] = {g0.x, g0.y, g0.z, g0.w, g1.x, g1.y, g1.z, g1.w};
    const float bb[8] = {b0.x, b0.y, b0.z, b0.w, b1v.x, b1v.y, b1v.z, b1v.w};
    const float wwv[8] = {w0.x, w0.y, w0.z, w0.w, w1v.x, w1v.y, w1v.z, w1v.w};
    float a = 0.f;
#pragma unroll
    for (int t = 0; t < 8; ++t) a += ((vv[t] - mu) * rstd * gg[t] + bb[t]) * wwv[t];
#pragma unroll
    for (int m = 32; m > 0; m >>= 1) a += __shfl_xor(a, m);
    if (lane == 0) srl[r] = a + wbias[0];
  }
  __syncthreads();
  if (threadIdx.x == 0) {
    float mx = -1e30f;
    for (int r = 0; r < R_; ++r)
      if (present[b * R_ + r]) mx = fmaxf(mx, srl[r]);
    float sm = 0.f;
    for (int r = 0; r < R_; ++r) {
      const float e = present[b * R_ + r] ? __expf(srl[r] - mx) : 0.f;
      srw[r] = e;
      sm += e;
    }
    const float inv = (sm > 0.f) ? 1.0f / sm : 0.f;
    for (int r = 0; r < R_; ++r) srw[r] *= inv;
  }
  __syncthreads();
  const int d = threadIdx.x;
  float a = 0.f;
  for (int r = 0; r < R_; ++r) a += srw[r] * routes[((size_t)b * R_ + r) * D_ + d];
  out[(size_t)b * D_ + d] = a;
}

// ---------------------------------------------------------------------------
extern "C" void kernel_launch(void* const* d_in, const int* in_sizes, int n_in,
                              void* d_out, int out_size, void* d_ws, size_t ws_size,
                              hipStream_t stream) {
  const float* tokens = (const float*)d_in[0];
  const void* mask_raw = d_in[1];
  const int* route_ids = (const int*)d_in[2];
  const float* ln1_g = (const float*)d_in[3];
  const float* ln1_b = (const float*)d_in[4];
  const float* w1 = (const float*)d_in[5];
  const float* b1 = (const float*)d_in[6];
  const float* w2 = (const float*)d_in[7];
  const float* b2 = (const float*)d_in[8];
  const float* wp_g = (const float*)d_in[9];
  const float* wp_b = (const float*)d_in[10];
  const float* wp_w = (const float*)d_in[11];
  const float* wp_bias = (const float*)d_in[12];
  const float* rp_g = (const float*)d_in[13];
  const float* rp_b = (const float*)d_in[14];
  const float* rp_w = (const float*)d_in[15];
  const float* rp_bias = (const float*)d_in[16];
  float* out = (float*)d_out;

  char* ws = (char*)d_ws;
  size_t off = 0;
  auto carve = [&](size_t bytes) -> void* {
    void* p = ws + off;
    off = (off + bytes + 255) & ~(size_t)255;
    return p;
  };

  __hip_bfloat16* w1t = (__hip_bfloat16*)carve((size_t)H_ * D_ * 2);  // [H, D]
  __hip_bfloat16* w2t = (__hip_bfloat16*)carve((size_t)D_ * H_ * 2);  // [D, H]
  __hip_bfloat16* aBf = (__hip_bfloat16*)carve((size_t)M_ * D_ * 2);  // LN1 out
  float* X = (float*)carve((size_t)M_ * D_ * 4);                      // FFN out
  int* flag = (int*)carve(256);
  float* scr = (float*)carve(256);
  float* stats = (float*)carve((size_t)3 * M_ * 4);  // Sx | Sxx | P
  int* present = (int*)carve((size_t)B_ * R_ * 4);
  float* routes = (float*)carve((size_t)B_ * R_ * D_ * 4);

  int G = 1;
  while (G < 16 && off + (size_t)M_ * (H_ / G) * 2 > ws_size) G <<= 1;
  const int Hg = H_ / G;
  __hip_bfloat16* hbuf = (__hip_bfloat16*)carve((size_t)M_ * Hg * 2);

  prep_kernel<<<513 + M_ / 8, 512, 0, stream>>>(
      tokens, mask_raw, ln1_g, ln1_b, w1, w2, wp_g, wp_b, wp_w,
      aBf, w1t, w2t, flag, scr, stats);

  const int NC1 = Hg / 128;
  for (int g = 0; g < G; ++g) {
    gemm_bias_gelu_kernel<<<(M_ / 128) * NC1, 256, 0, stream>>>(
        aBf, w1t + (size_t)g * Hg * D_, b1 + (size_t)g * Hg, hbuf, D_, Hg, NC1);
    gemm_acc_kernel<<<(M_ / 256) * 4, 512, 0, stream>>>(
        hbuf, w2t + (size_t)g * Hg, b2, tokens, X, wp_g, wp_w, stats,
        Hg, H_, (g == 0) ? 1 : 0, (g == G - 1) ? 1 : 0);
  }

  route_pool_kernel<<<B_ * R_, 256, 0, stream>>>(
      X, route_ids, mask_raw, flag, scr, stats, wp_bias, routes, present);
  final_pool_kernel<<<B_, 512, 0, stream>>>(routes, present, rp_g, rp_b, rp_w, rp_bias, out);
}